// Round 3
// baseline (753.469 us; speedup 1.0000x reference)
//
#include <hip/hip_runtime.h>
#include <hip/hip_bf16.h>

#define NH 16
#define HD 64
#define ED 1024
#define BS 4
#define SL 2048

typedef _Float16 f16x8 __attribute__((ext_vector_type(8)));
typedef _Float16 f16x4 __attribute__((ext_vector_type(4)));
typedef _Float16 f16x2 __attribute__((ext_vector_type(2)));
typedef float floatx4 __attribute__((ext_vector_type(4)));

// ---------------------------------------------------------------------------
// Weight pre-convert: fp32 [ED][ED] -> fp16, for Wq/Wk/Wv (into ws slotB,
// which is later reused as attnOut once the weights are consumed).
// ---------------------------------------------------------------------------
__global__ __launch_bounds__(256) void cvtw_kernel(const float* __restrict__ Wq,
                                                   const float* __restrict__ Wk,
                                                   const float* __restrict__ Wv,
                                                   _Float16* __restrict__ Wh)
{
    const float* W = (blockIdx.y == 0) ? Wq : (blockIdx.y == 1) ? Wk : Wv;
    _Float16* out = Wh + (size_t)blockIdx.y * (ED * ED);
    const int i = (blockIdx.x * 256 + threadIdx.x) * 4;
    float4 v = *(const float4*)(W + i);
    f16x4 c;
    c[0] = (_Float16)v.x; c[1] = (_Float16)v.y;
    c[2] = (_Float16)v.z; c[3] = (_Float16)v.w;
    *(f16x4*)(out + i) = c;
}

// ---------------------------------------------------------------------------
// GEMM: C = A[MxK] * B[NxK]^T, 128x128 tile per 256-thread block.
// (unchanged from round 2)
// ---------------------------------------------------------------------------
__device__ __forceinline__ int lds_boff(int kq, int rc)
{
    return (((kq << 7) + rc) << 4) ^ (kq << 5);   // byte offset
}

template <int A_MODE, int B_MODE, int OUT_MODE>
__device__ __forceinline__ void gemm128_body(const float* __restrict__ Af,
                                             const _Float16* __restrict__ Ah,
                                             const float* __restrict__ Bf,
                                             const _Float16* __restrict__ Bh,
                                             _Float16* __restrict__ outH,
                                             float* __restrict__ outF,
                                             int K, int N)
{
    __shared__ __align__(16) _Float16 As[4 * 128 * 8];   // 8 KB
    __shared__ __align__(16) _Float16 Bs[4 * 128 * 8];   // 8 KB

    const int tid  = threadIdx.x;
    const int wave = tid >> 6;
    const int lane = tid & 63;
    const int lo16 = lane & 15;
    const int hi4  = lane >> 4;
    const int wm = wave >> 1;
    const int wn = wave & 1;
    const int rowTile = blockIdx.y * 128;
    const int colTile = blockIdx.x * 128;

    floatx4 acc[4][4];
#pragma unroll
    for (int m = 0; m < 4; m++)
#pragma unroll
        for (int n = 0; n < 4; n++)
            acc[m][n] = (floatx4){0.f, 0.f, 0.f, 0.f};

    for (int kb = 0; kb < K; kb += 32) {
        float4 aF[4]; f16x8 aH[2];
        if (A_MODE == 0) {
#pragma unroll
            for (int r = 0; r < 4; r++) {
                const int t2 = tid + r * 256;
                const int row = t2 >> 3;
                const int k4 = (t2 & 7) * 4;
                aF[r] = *(const float4*)(Af + (size_t)(rowTile + row) * K + kb + k4);
            }
        } else {
#pragma unroll
            for (int r = 0; r < 2; r++) {
                const int t2 = tid + r * 256;
                const int row = t2 >> 2;
                const int ko = (t2 & 3) * 8;
                const int gr = rowTile + row;
                const int b = gr >> 11;
                const int s = gr & (SL - 1);
                const int k0 = kb + ko;
                const int h = k0 >> 6;
                const int d = k0 & (HD - 1);
                aH[r] = *(const f16x8*)(Ah + (((size_t)(b * NH + h)) * SL + s) * HD + d);
            }
        }
        f16x8 bH[2]; float4 bF[4];
        if (B_MODE == 0) {
#pragma unroll
            for (int r = 0; r < 2; r++) {
                const int t2 = tid + r * 256;
                const int col = t2 >> 2;
                const int ko = (t2 & 3) * 8;
                bH[r] = *(const f16x8*)(Bh + (size_t)(colTile + col) * K + kb + ko);
            }
        } else {
#pragma unroll
            for (int r = 0; r < 4; r++) {
                const int t2 = tid + r * 256;
                const int col = t2 >> 3;
                const int k4 = (t2 & 7) * 4;
                bF[r] = *(const float4*)(Bf + (size_t)(colTile + col) * K + kb + k4);
            }
        }

        __syncthreads();                       // prior K-step frag reads done
        if (A_MODE == 0) {
#pragma unroll
            for (int r = 0; r < 4; r++) {
                const int t2 = tid + r * 256;
                const int row = t2 >> 3;
                const int k4 = (t2 & 7) * 4;
                f16x4 c;
                c[0] = (_Float16)aF[r].x; c[1] = (_Float16)aF[r].y;
                c[2] = (_Float16)aF[r].z; c[3] = (_Float16)aF[r].w;
                *(f16x4*)((char*)As + lds_boff(k4 >> 3, row) + (k4 & 7) * 2) = c;
            }
        } else {
#pragma unroll
            for (int r = 0; r < 2; r++) {
                const int t2 = tid + r * 256;
                const int row = t2 >> 2;
                const int ko = (t2 & 3) * 8;
                *(f16x8*)((char*)As + lds_boff(ko >> 3, row)) = aH[r];
            }
        }
        if (B_MODE == 0) {
#pragma unroll
            for (int r = 0; r < 2; r++) {
                const int t2 = tid + r * 256;
                const int col = t2 >> 2;
                const int ko = (t2 & 3) * 8;
                *(f16x8*)((char*)Bs + lds_boff(ko >> 3, col)) = bH[r];
            }
        } else {
#pragma unroll
            for (int r = 0; r < 4; r++) {
                const int t2 = tid + r * 256;
                const int col = t2 >> 3;
                const int k4 = (t2 & 7) * 4;
                f16x4 c;
                c[0] = (_Float16)bF[r].x; c[1] = (_Float16)bF[r].y;
                c[2] = (_Float16)bF[r].z; c[3] = (_Float16)bF[r].w;
                *(f16x4*)((char*)Bs + lds_boff(k4 >> 3, col) + (k4 & 7) * 2) = c;
            }
        }
        __syncthreads();

        f16x8 af[4], bfr[4];
#pragma unroll
        for (int m = 0; m < 4; m++)
            af[m] = *(const f16x8*)((char*)As + lds_boff(hi4, wm * 64 + m * 16 + lo16));
#pragma unroll
        for (int n = 0; n < 4; n++)
            bfr[n] = *(const f16x8*)((char*)Bs + lds_boff(hi4, wn * 64 + n * 16 + lo16));
#pragma unroll
        for (int m = 0; m < 4; m++)
#pragma unroll
            for (int n = 0; n < 4; n++)
                acc[m][n] = __builtin_amdgcn_mfma_f32_16x16x32_f16(af[m], bfr[n], acc[m][n], 0, 0, 0);
    }

#pragma unroll
    for (int m = 0; m < 4; m++) {
#pragma unroll
        for (int n = 0; n < 4; n++) {
            const int col = colTile + wn * 64 + n * 16 + lo16;
#pragma unroll
            for (int i = 0; i < 4; i++) {
                const int row = rowTile + wm * 64 + m * 16 + hi4 * 4 + i;
                float v = acc[m][n][i];
                if (OUT_MODE == 0) {
                    int b = row >> 11;
                    int s = row & (SL - 1);
                    int h = col >> 6;
                    int d = col & (HD - 1);
                    outH[(((size_t)(b * NH + h)) * SL + s) * HD + d] = (_Float16)v;
                } else {
                    outF[(size_t)row * N + col] = v;
                }
            }
        }
    }
}

__global__ __launch_bounds__(256) void qkv_kernel(const float* __restrict__ x,
                                                  const _Float16* __restrict__ Wh,
                                                  _Float16* __restrict__ Q,
                                                  _Float16* __restrict__ Kk,
                                                  _Float16* __restrict__ V)
{
    const _Float16* W = Wh + (size_t)blockIdx.z * (ED * ED);
    _Float16* out = (blockIdx.z == 0) ? Q : (blockIdx.z == 1) ? Kk : V;
    gemm128_body<0, 0, 0>(x, nullptr, nullptr, W, out, nullptr, ED, ED);
}

__global__ __launch_bounds__(256) void oproj_kernel(const _Float16* __restrict__ A,
                                                    const float* __restrict__ Wo,
                                                    float* __restrict__ out)
{
    gemm128_body<1, 1, 1>(nullptr, A, Wo, nullptr, nullptr, out, ED, ED);
}

// ---------------------------------------------------------------------------
// MFMA flash attention, round 3.
// Block = 256 threads = 4 waves; q-tile 128 rows (wave owns 32 = 2 m-tiles).
// KV chunk = 64 keys. Per wave per chunk: 16 QK^T + 16 PV MFMAs.
// Round-3 changes:
//  - grid (qt, b, h): bias-panel sharers (4 batches) are 16 block-ids apart
//    => same XCD (id%8) => bias served from L2 for 3 of 4 readers.
//  - bias staged through LDS (fp16, stride 68 => conflict-free group reads);
//    8 coalesced float4 loads/thread at loop top instead of 32 serial scalar
//    loads inside softmax.
//  - K/V next-chunk carry-prefetch across the compute phase (T14).
//  - defer-max (T13, THR=8): skip alpha-rescale while rmax <= m+8.
//  - s_setprio(1) around MFMA clusters (T5).
// ---------------------------------------------------------------------------
__global__ __launch_bounds__(256) void attn_kernel(const _Float16* __restrict__ Qg,
                                                   const _Float16* __restrict__ Kg,
                                                   const _Float16* __restrict__ Vg,
                                                   const float* __restrict__ bias,
                                                   _Float16* __restrict__ attnOut)
{
    __shared__ __align__(16) _Float16 Ks[8 * 64 * 8];    // 8 KB
    __shared__ __align__(16) _Float16 Vt[64 * 64];       // 8 KB
    __shared__ __align__(16) _Float16 Ps[4 * 32 * 64];   // 16 KB
    __shared__ __align__(16) _Float16 Bi[128 * 68];      // 17 KB

    const int qt = blockIdx.x;
    const int b  = blockIdx.y;
    const int h  = blockIdx.z;
    const int bh = b * NH + h;
    const int tid  = threadIdx.x;
    const int wave = tid >> 6;
    const int lane = tid & 63;
    const int lo16 = lane & 15;
    const int hi4  = lane >> 4;

    const _Float16* Qbh = Qg + (size_t)bh * SL * HD;
    const _Float16* Kbh = Kg + (size_t)bh * SL * HD;
    const _Float16* Vbh = Vg + (size_t)bh * SL * HD;
    const float* biasH = bias + (size_t)h * SL * SL;

    const int q0 = qt * 128 + wave * 32;

    // Q fragments, resident all kernel
    f16x8 qf[2][2];
#pragma unroll
    for (int m = 0; m < 2; m++)
#pragma unroll
        for (int ks = 0; ks < 2; ks++)
            qf[m][ks] = *(const f16x8*)(Qbh + (size_t)(q0 + m * 16 + lo16) * HD
                                        + ks * 32 + hi4 * 8);

    floatx4 oAcc[2][4];
    float mRow[2][4], lRow[2][4];
#pragma unroll
    for (int m = 0; m < 2; m++)
#pragma unroll
        for (int n = 0; n < 4; n++)
            oAcc[m][n] = (floatx4){0.f, 0.f, 0.f, 0.f};
#pragma unroll
    for (int m = 0; m < 2; m++)
#pragma unroll
        for (int r = 0; r < 4; r++) { mRow[m][r] = -1e30f; lRow[m][r] = 0.f; }

    // staging maps
    const int kKey = tid >> 2;
    const int kD0  = (tid & 3) * 8;
    _Float16* kDst0 = Ks + (((kKey >> 4)     ) * 64 + (kKey & 15) + 16 * (kD0 >> 3)) * 8;
    _Float16* kDst1 = Ks + (((kKey >> 4) + 4) * 64 + (kKey & 15) + 16 * (kD0 >> 3)) * 8;
    const int vK0 = (tid >> 3) * 2;
    const int vD0 = (tid & 7) * 8;

    // bias staging map: 16 threads cover one 64-col row (4 floats each)
    const int bRow = tid >> 4;          // 0..15 (+16 per r-step)
    const int bCol = (tid & 15) * 4;    // 0..60
    const float* bThr = biasH + ((size_t)(qt * 128) + bRow) * SL + bCol;

    // prologue: carry-load chunk 0 K/V
    f16x8 ka = *(const f16x8*)(Kbh + (size_t)(0 + kKey) * HD + kD0);
    f16x8 kb = *(const f16x8*)(Kbh + (size_t)(0 + kKey) * HD + kD0 + 32);
    f16x8 va = *(const f16x8*)(Vbh + (size_t)(0 + vK0    ) * HD + vD0);
    f16x8 vb = *(const f16x8*)(Vbh + (size_t)(0 + vK0 + 1) * HD + vD0);

    for (int kc = 0; kc < SL; kc += 64) {
        // bias loads for THIS chunk (batched, coalesced; consumed after sync)
        float4 bld[8];
#pragma unroll
        for (int r = 0; r < 8; r++)
            bld[r] = *(const float4*)(bThr + (size_t)r * 16 * SL + kc);

        __syncthreads();                 // prior chunk's LDS reads complete
        *(f16x8*)kDst0 = ka;
        *(f16x8*)kDst1 = kb;
#pragma unroll
        for (int i = 0; i < 8; i++) {
            const int d = vD0 + i;
            const int sw = (d & 7) ^ ((d >> 3) & 7);
            char* p = (char*)Vt + (d << 7)
                      + ((((vK0 >> 3) ^ sw) & 7) << 4) + ((vK0 & 7) << 1);
            f16x2 pr; pr[0] = va[i]; pr[1] = vb[i];
            *(f16x2*)p = pr;
        }
#pragma unroll
        for (int r = 0; r < 8; r++) {
            f16x4 c;
            c[0] = (_Float16)bld[r].x; c[1] = (_Float16)bld[r].y;
            c[2] = (_Float16)bld[r].z; c[3] = (_Float16)bld[r].w;
            *(f16x4*)(Bi + (bRow + r * 16) * 68 + bCol) = c;
        }
        __syncthreads();                 // staging visible

        // carry-prefetch next chunk K/V (latency hides under compute)
        {
            const int kn = (kc + 64 < SL) ? kc + 64 : kc;
            ka = *(const f16x8*)(Kbh + (size_t)(kn + kKey) * HD + kD0);
            kb = *(const f16x8*)(Kbh + (size_t)(kn + kKey) * HD + kD0 + 32);
            va = *(const f16x8*)(Vbh + (size_t)(kn + vK0    ) * HD + vD0);
            vb = *(const f16x8*)(Vbh + (size_t)(kn + vK0 + 1) * HD + vD0);
        }

        // ---- S = Q K^T ----
        floatx4 s[2][4];
#pragma unroll
        for (int m = 0; m < 2; m++)
#pragma unroll
            for (int n = 0; n < 4; n++)
                s[m][n] = (floatx4){0.f, 0.f, 0.f, 0.f};
        __builtin_amdgcn_s_setprio(1);
#pragma unroll
        for (int ks = 0; ks < 2; ks++)
#pragma unroll
            for (int n = 0; n < 4; n++) {
                f16x8 kf = *(const f16x8*)(Ks + ((ks * 4 + n) * 64 + lane) * 8);
                s[0][n] = __builtin_amdgcn_mfma_f32_16x16x32_f16(qf[0][ks], kf, s[0][n], 0, 0, 0);
                s[1][n] = __builtin_amdgcn_mfma_f32_16x16x32_f16(qf[1][ks], kf, s[1][n], 0, 0, 0);
            }
        __builtin_amdgcn_s_setprio(0);

        // ---- bias (from LDS) + online softmax with defer-max ----
#pragma unroll
        for (int m = 0; m < 2; m++)
#pragma unroll
            for (int r = 0; r < 4; r++) {
                const int ql = m * 16 + hi4 * 4 + r;     // wave-local q 0..31
                const _Float16* bsr = Bi + (wave * 32 + ql) * 68;
                float s0 = s[m][0][r] + (float)bsr[lo16];
                float s1 = s[m][1][r] + (float)bsr[16 + lo16];
                float s2 = s[m][2][r] + (float)bsr[32 + lo16];
                float s3 = s[m][3][r] + (float)bsr[48 + lo16];
                float rmax = fmaxf(fmaxf(s0, s1), fmaxf(s2, s3));
                rmax = fmaxf(rmax, __shfl_xor(rmax, 1));
                rmax = fmaxf(rmax, __shfl_xor(rmax, 2));
                rmax = fmaxf(rmax, __shfl_xor(rmax, 4));
                rmax = fmaxf(rmax, __shfl_xor(rmax, 8));
                float mCur = mRow[m][r];
                if (rmax > mCur + 8.f) {                 // defer-max (T13)
                    const float alpha = __expf(mCur - rmax);
                    mCur = rmax;
                    mRow[m][r] = rmax;
                    lRow[m][r] *= alpha;
#pragma unroll
                    for (int n = 0; n < 4; n++) oAcc[m][n][r] *= alpha;
                }
                float p0 = __expf(s0 - mCur);            // bounded by e^8
                float p1 = __expf(s1 - mCur);
                float p2 = __expf(s2 - mCur);
                float p3 = __expf(s3 - mCur);
                float rsum = (p0 + p1) + (p2 + p3);
                rsum += __shfl_xor(rsum, 1);
                rsum += __shfl_xor(rsum, 2);
                rsum += __shfl_xor(rsum, 4);
                rsum += __shfl_xor(rsum, 8);
                lRow[m][r] += rsum;

                char* pb = (char*)Ps + (wave << 12) + (ql << 7) + ((lo16 & 7) << 1);
                const int kb3 = lo16 >> 3;
                const int swp = (ql & 7) ^ (((ql >> 3) & 3) << 1);
                *(_Float16*)(pb + ((((0 + kb3) ^ swp) & 7) << 4)) = (_Float16)p0;
                *(_Float16*)(pb + ((((2 + kb3) ^ swp) & 7) << 4)) = (_Float16)p1;
                *(_Float16*)(pb + ((((4 + kb3) ^ swp) & 7) << 4)) = (_Float16)p2;
                *(_Float16*)(pb + ((((6 + kb3) ^ swp) & 7) << 4)) = (_Float16)p3;
            }

        // ---- O += P V ----
        __builtin_amdgcn_s_setprio(1);
#pragma unroll
        for (int ks = 0; ks < 2; ks++) {
            f16x8 pa[2];
#pragma unroll
            for (int m = 0; m < 2; m++) {
                const int qlr = m * 16 + lo16;
                const int swp = (qlr & 7) ^ (((qlr >> 3) & 3) << 1);
                pa[m] = *(const f16x8*)((char*)Ps + (wave << 12) + (qlr << 7)
                                        + ((((ks * 4 + hi4) ^ swp) & 7) << 4));
            }
#pragma unroll
            for (int n = 0; n < 4; n++) {
                const int dv = n * 16 + lo16;
                const int swv = (dv & 7) ^ ((dv >> 3) & 7);
                f16x8 vf = *(const f16x8*)((char*)Vt + (dv << 7)
                                           + ((((ks * 4 + hi4) ^ swv) & 7) << 4));
                oAcc[0][n] = __builtin_amdgcn_mfma_f32_16x16x32_f16(pa[0], vf, oAcc[0][n], 0, 0, 0);
                oAcc[1][n] = __builtin_amdgcn_mfma_f32_16x16x32_f16(pa[1], vf, oAcc[1][n], 0, 0, 0);
            }
        }
        __builtin_amdgcn_s_setprio(0);
    }

    // ---- epilogue: O / l -> fp16 [b,h,s,d] ----
#pragma unroll
    for (int m = 0; m < 2; m++)
#pragma unroll
        for (int r = 0; r < 4; r++) {
            const float inv = 1.f / lRow[m][r];
            const int q = q0 + m * 16 + hi4 * 4 + r;
#pragma unroll
            for (int n = 0; n < 4; n++)
                attnOut[((size_t)bh * SL + q) * HD + n * 16 + lo16] =
                    (_Float16)(oAcc[m][n][r] * inv);
        }
}

extern "C" void kernel_launch(void* const* d_in, const int* in_sizes, int n_in,
                              void* d_out, int out_size, void* d_ws, size_t ws_size,
                              hipStream_t stream)
{
    (void)in_sizes; (void)n_in; (void)out_size; (void)ws_size;

    const float* x    = (const float*)d_in[0];
    const float* bias = (const float*)d_in[1];
    const float* Wq   = (const float*)d_in[2];
    const float* Wk   = (const float*)d_in[3];
    const float* Wv   = (const float*)d_in[4];
    const float* Wo   = (const float*)d_in[5];

    const size_t nQKV = (size_t)BS * NH * SL * HD;   // 8388608 elements
    // d_out: Q,K fp16 (2 x 16.78 MB). ws: [V 16.78MB][slotB 16.78MB].
    // slotB = Wh(q,k,v fp16, 6.3MB) during qkv; then attnH (16.78MB) after.
    _Float16* Qh = (_Float16*)d_out;
    _Float16* Kh = Qh + nQKV;
    _Float16* Vh = (_Float16*)d_ws;
    _Float16* slotB = Vh + nQKV;
    _Float16* Wh = slotB;
    _Float16* attnH = slotB;

    // 0) convert Wq/Wk/Wv to fp16
    cvtw_kernel<<<dim3(ED * ED / 1024, 3), 256, 0, stream>>>(Wq, Wk, Wv, Wh);

    // 1) QKV projections: [8192x1024] @ W^T -> fp16 [b,h,s,d]
    dim3 gq(ED / 128, (BS * SL) / 128, 3);
    qkv_kernel<<<gq, 256, 0, stream>>>(x, Wh, Qh, Kh, Vh);

    // 2) MFMA flash attention with rel-pos bias -> fp16 [b,h,s,d] (slotB)
    //    grid (qt, b, h): bias-panel sharers land on the same XCD.
    dim3 ga(SL / 128, BS, NH);
    attn_kernel<<<ga, 256, 0, stream>>>(Qh, Kh, Vh, bias, attnH);

    // 3) output projection (gather A from [b,h,s,d]) -> d_out fp32
    dim3 go(ED / 128, (BS * SL) / 128);
    oproj_kernel<<<go, 256, 0, stream>>>(attnH, Wo, (float*)d_out);
}

// Round 5
// 643.224 us; speedup vs baseline: 1.1714x; 1.1714x over previous
//
#include <hip/hip_runtime.h>
#include <hip/hip_bf16.h>

#define NH 16
#define HD 64
#define ED 1024
#define BS 4
#define SL 2048

typedef _Float16 f16x8 __attribute__((ext_vector_type(8)));
typedef _Float16 f16x4 __attribute__((ext_vector_type(4)));
typedef _Float16 f16x2 __attribute__((ext_vector_type(2)));
typedef float floatx4 __attribute__((ext_vector_type(4)));

// ---------------------------------------------------------------------------
// Weight pre-convert: fp32 [ED][ED] -> fp16, for Wq/Wk/Wv (into ws slotB,
// which is later reused as attnOut once the weights are consumed).
// ---------------------------------------------------------------------------
__global__ __launch_bounds__(256) void cvtw_kernel(const float* __restrict__ Wq,
                                                   const float* __restrict__ Wk,
                                                   const float* __restrict__ Wv,
                                                   _Float16* __restrict__ Wh)
{
    const float* W = (blockIdx.y == 0) ? Wq : (blockIdx.y == 1) ? Wk : Wv;
    _Float16* out = Wh + (size_t)blockIdx.y * (ED * ED);
    const int i = (blockIdx.x * 256 + threadIdx.x) * 4;
    float4 v = *(const float4*)(W + i);
    f16x4 c;
    c[0] = (_Float16)v.x; c[1] = (_Float16)v.y;
    c[2] = (_Float16)v.z; c[3] = (_Float16)v.w;
    *(f16x4*)(out + i) = c;
}

// ---------------------------------------------------------------------------
// GEMM: C = A[MxK] * B[NxK]^T, 128x128 tile per 256-thread block.
// (unchanged from rounds 2/3 — verified)
// ---------------------------------------------------------------------------
__device__ __forceinline__ int lds_boff(int kq, int rc)
{
    return (((kq << 7) + rc) << 4) ^ (kq << 5);   // byte offset
}

template <int A_MODE, int B_MODE, int OUT_MODE>
__device__ __forceinline__ void gemm128_body(const float* __restrict__ Af,
                                             const _Float16* __restrict__ Ah,
                                             const float* __restrict__ Bf,
                                             const _Float16* __restrict__ Bh,
                                             _Float16* __restrict__ outH,
                                             float* __restrict__ outF,
                                             int K, int N)
{
    __shared__ __align__(16) _Float16 As[4 * 128 * 8];   // 8 KB
    __shared__ __align__(16) _Float16 Bs[4 * 128 * 8];   // 8 KB

    const int tid  = threadIdx.x;
    const int wave = tid >> 6;
    const int lane = tid & 63;
    const int lo16 = lane & 15;
    const int hi4  = lane >> 4;
    const int wm = wave >> 1;
    const int wn = wave & 1;
    const int rowTile = blockIdx.y * 128;
    const int colTile = blockIdx.x * 128;

    floatx4 acc[4][4];
#pragma unroll
    for (int m = 0; m < 4; m++)
#pragma unroll
        for (int n = 0; n < 4; n++)
            acc[m][n] = (floatx4){0.f, 0.f, 0.f, 0.f};

    for (int kb = 0; kb < K; kb += 32) {
        float4 aF[4]; f16x8 aH[2];
        if (A_MODE == 0) {
#pragma unroll
            for (int r = 0; r < 4; r++) {
                const int t2 = tid + r * 256;
                const int row = t2 >> 3;
                const int k4 = (t2 & 7) * 4;
                aF[r] = *(const float4*)(Af + (size_t)(rowTile + row) * K + kb + k4);
            }
        } else {
#pragma unroll
            for (int r = 0; r < 2; r++) {
                const int t2 = tid + r * 256;
                const int row = t2 >> 2;
                const int ko = (t2 & 3) * 8;
                const int gr = rowTile + row;
                const int b = gr >> 11;
                const int s = gr & (SL - 1);
                const int k0 = kb + ko;
                const int h = k0 >> 6;
                const int d = k0 & (HD - 1);
                aH[r] = *(const f16x8*)(Ah + (((size_t)(b * NH + h)) * SL + s) * HD + d);
            }
        }
        f16x8 bH[2]; float4 bF[4];
        if (B_MODE == 0) {
#pragma unroll
            for (int r = 0; r < 2; r++) {
                const int t2 = tid + r * 256;
                const int col = t2 >> 2;
                const int ko = (t2 & 3) * 8;
                bH[r] = *(const f16x8*)(Bh + (size_t)(colTile + col) * K + kb + ko);
            }
        } else {
#pragma unroll
            for (int r = 0; r < 4; r++) {
                const int t2 = tid + r * 256;
                const int col = t2 >> 3;
                const int k4 = (t2 & 7) * 4;
                bF[r] = *(const float4*)(Bf + (size_t)(colTile + col) * K + kb + k4);
            }
        }

        __syncthreads();                       // prior K-step frag reads done
        if (A_MODE == 0) {
#pragma unroll
            for (int r = 0; r < 4; r++) {
                const int t2 = tid + r * 256;
                const int row = t2 >> 3;
                const int k4 = (t2 & 7) * 4;
                f16x4 c;
                c[0] = (_Float16)aF[r].x; c[1] = (_Float16)aF[r].y;
                c[2] = (_Float16)aF[r].z; c[3] = (_Float16)aF[r].w;
                *(f16x4*)((char*)As + lds_boff(k4 >> 3, row) + (k4 & 7) * 2) = c;
            }
        } else {
#pragma unroll
            for (int r = 0; r < 2; r++) {
                const int t2 = tid + r * 256;
                const int row = t2 >> 2;
                const int ko = (t2 & 3) * 8;
                *(f16x8*)((char*)As + lds_boff(ko >> 3, row)) = aH[r];
            }
        }
        if (B_MODE == 0) {
#pragma unroll
            for (int r = 0; r < 2; r++) {
                const int t2 = tid + r * 256;
                const int col = t2 >> 2;
                const int ko = (t2 & 3) * 8;
                *(f16x8*)((char*)Bs + lds_boff(ko >> 3, col)) = bH[r];
            }
        } else {
#pragma unroll
            for (int r = 0; r < 4; r++) {
                const int t2 = tid + r * 256;
                const int col = t2 >> 3;
                const int k4 = (t2 & 7) * 4;
                f16x4 c;
                c[0] = (_Float16)bF[r].x; c[1] = (_Float16)bF[r].y;
                c[2] = (_Float16)bF[r].z; c[3] = (_Float16)bF[r].w;
                *(f16x4*)((char*)Bs + lds_boff(k4 >> 3, col) + (k4 & 7) * 2) = c;
            }
        }
        __syncthreads();

        f16x8 af[4], bfr[4];
#pragma unroll
        for (int m = 0; m < 4; m++)
            af[m] = *(const f16x8*)((char*)As + lds_boff(hi4, wm * 64 + m * 16 + lo16));
#pragma unroll
        for (int n = 0; n < 4; n++)
            bfr[n] = *(const f16x8*)((char*)Bs + lds_boff(hi4, wn * 64 + n * 16 + lo16));
#pragma unroll
        for (int m = 0; m < 4; m++)
#pragma unroll
            for (int n = 0; n < 4; n++)
                acc[m][n] = __builtin_amdgcn_mfma_f32_16x16x32_f16(af[m], bfr[n], acc[m][n], 0, 0, 0);
    }

#pragma unroll
    for (int m = 0; m < 4; m++) {
#pragma unroll
        for (int n = 0; n < 4; n++) {
            const int col = colTile + wn * 64 + n * 16 + lo16;
#pragma unroll
            for (int i = 0; i < 4; i++) {
                const int row = rowTile + wm * 64 + m * 16 + hi4 * 4 + i;
                float v = acc[m][n][i];
                if (OUT_MODE == 0) {
                    int b = row >> 11;
                    int s = row & (SL - 1);
                    int h = col >> 6;
                    int d = col & (HD - 1);
                    outH[(((size_t)(b * NH + h)) * SL + s) * HD + d] = (_Float16)v;
                } else {
                    outF[(size_t)row * N + col] = v;
                }
            }
        }
    }
}

__global__ __launch_bounds__(256) void qkv_kernel(const float* __restrict__ x,
                                                  const _Float16* __restrict__ Wh,
                                                  _Float16* __restrict__ Q,
                                                  _Float16* __restrict__ Kk,
                                                  _Float16* __restrict__ V)
{
    const _Float16* W = Wh + (size_t)blockIdx.z * (ED * ED);
    _Float16* out = (blockIdx.z == 0) ? Q : (blockIdx.z == 1) ? Kk : V;
    gemm128_body<0, 0, 0>(x, nullptr, nullptr, W, out, nullptr, ED, ED);
}

__global__ __launch_bounds__(256) void oproj_kernel(const _Float16* __restrict__ A,
                                                    const float* __restrict__ Wo,
                                                    float* __restrict__ out)
{
    gemm128_body<1, 1, 1>(nullptr, A, Wo, nullptr, nullptr, out, ED, ED);
}

// ---------------------------------------------------------------------------
// MFMA flash attention, round 4 (resubmit after infra failure):
// transposed score tile.
// Block = 256 threads = 4 waves; q-tile 128 rows (wave owns 32).
// KV chunk = 64. Per wave per chunk: 16 QK^T + 16 PV MFMAs.
// Key change: S^T = mfma(K_frag, Q_frag) -> lane holds S^T[key][q] with 16
// in-lane keys (4 mk-tiles x 4 regs) and only 4 lanes per q row:
//  - row max/sum = 15 in-lane ops + 2 shfl_xor (16,32)  [was 8x8 shuffles]
//  - bias: one float4 global load per (nq,mk), fp32 add, no LDS staging
//  - P-writes: f16x4 (8B) into the same verified Ps swizzle
//  - PV swapped too: O^T = mfma(V^T_frag, P_frag); epilogue f16x4 stores
//  - K/V LDS double-buffered: ONE barrier per chunk; carry-prefetch crosses
//    no barrier (issue post-barrier, consume next-iter pre-barrier).
// ---------------------------------------------------------------------------
__global__ __launch_bounds__(256) void attn_kernel(const _Float16* __restrict__ Qg,
                                                   const _Float16* __restrict__ Kg,
                                                   const _Float16* __restrict__ Vg,
                                                   const float* __restrict__ bias,
                                                   _Float16* __restrict__ attnOut)
{
    __shared__ __align__(16) _Float16 Ks[2][8 * 64 * 8];   // 2 x 8 KB
    __shared__ __align__(16) _Float16 Vt[2][64 * 64];      // 2 x 8 KB
    __shared__ __align__(16) _Float16 Ps[4 * 32 * 64];     // 16 KB

    const int qt = blockIdx.x;
    const int b  = blockIdx.y;
    const int h  = blockIdx.z;
    const int bh = b * NH + h;
    const int tid  = threadIdx.x;
    const int wave = tid >> 6;
    const int lane = tid & 63;
    const int lo16 = lane & 15;
    const int hi4  = lane >> 4;

    const _Float16* Qbh = Qg + (size_t)bh * SL * HD;
    const _Float16* Kbh = Kg + (size_t)bh * SL * HD;
    const _Float16* Vbh = Vg + (size_t)bh * SL * HD;
    const float* biasH = bias + (size_t)h * SL * SL;

    const int q0 = qt * 128 + wave * 32;

    // Q as B-frags (col=q, k=d): qf[nq][ks]
    f16x8 qf[2][2];
#pragma unroll
    for (int nq = 0; nq < 2; nq++)
#pragma unroll
        for (int ks = 0; ks < 2; ks++)
            qf[nq][ks] = *(const f16x8*)(Qbh + (size_t)(q0 + nq * 16 + lo16) * HD
                                         + ks * 32 + hi4 * 8);

    // O^T accumulators: oT[m(d-tile)][nq], rows d = m*16+hi4*4+reg, col q
    floatx4 oT[4][2];
#pragma unroll
    for (int m = 0; m < 4; m++)
#pragma unroll
        for (int nq = 0; nq < 2; nq++)
            oT[m][nq] = (floatx4){0.f, 0.f, 0.f, 0.f};
    float mRow[2] = {-1e30f, -1e30f};
    float lRow[2] = {0.f, 0.f};

    // staging maps (unchanged, verified)
    const int kKey = tid >> 2;
    const int kD0  = (tid & 3) * 8;
    const int kOff0 = (((kKey >> 4)    ) * 64 + (kKey & 15) + 16 * (kD0 >> 3)) * 8;
    const int kOff1 = (((kKey >> 4) + 4) * 64 + (kKey & 15) + 16 * (kD0 >> 3)) * 8;
    const int vK0 = (tid >> 3) * 2;
    const int vD0 = (tid & 7) * 8;

    // bias row bases (per-lane): row q0+nq*16+lo16, col kc + mk*16 + hi4*4
    const float* bRow0 = biasH + (size_t)(q0 + lo16) * SL + hi4 * 4;
    const float* bRow1 = biasH + (size_t)(q0 + 16 + lo16) * SL + hi4 * 4;

    // P swizzle constant for this lane's two q rows
    const int qA = lo16;              // nq=0 wave-local q
    const int qB = 16 + lo16;         // nq=1
    const int swpA = (qA & 7) ^ (((qA >> 3) & 3) << 1);
    const int swpB = (qB & 7) ^ (((qB >> 3) & 3) << 1);
    char* psW = (char*)Ps + (wave << 12);

    // prologue: chunk-0 K/V into carry regs
    f16x8 ka = *(const f16x8*)(Kbh + (size_t)(kKey) * HD + kD0);
    f16x8 kb = *(const f16x8*)(Kbh + (size_t)(kKey) * HD + kD0 + 32);
    f16x8 va = *(const f16x8*)(Vbh + (size_t)(vK0    ) * HD + vD0);
    f16x8 vb = *(const f16x8*)(Vbh + (size_t)(vK0 + 1) * HD + vD0);

    for (int kc = 0; kc < SL; kc += 64) {
        const int buf = (kc >> 6) & 1;
        // ---- consume carry regs -> LDS[buf] ----
        *(f16x8*)(Ks[buf] + kOff0) = ka;
        *(f16x8*)(Ks[buf] + kOff1) = kb;
#pragma unroll
        for (int i = 0; i < 8; i++) {
            const int d = vD0 + i;
            const int sw = (d & 7) ^ ((d >> 3) & 7);
            char* p = (char*)Vt[buf] + (d << 7)
                      + ((((vK0 >> 3) ^ sw) & 7) << 4) + ((vK0 & 7) << 1);
            f16x2 pr; pr[0] = va[i]; pr[1] = vb[i];
            *(f16x2*)p = pr;
        }
        __syncthreads();                 // staging visible; prior-buf reads done

        // ---- prefetch next chunk K/V (no barrier between issue & consume) ----
        {
            const int kn = (kc + 64 < SL) ? kc + 64 : kc;
            ka = *(const f16x8*)(Kbh + (size_t)(kn + kKey) * HD + kD0);
            kb = *(const f16x8*)(Kbh + (size_t)(kn + kKey) * HD + kD0 + 32);
            va = *(const f16x8*)(Vbh + (size_t)(kn + vK0    ) * HD + vD0);
            vb = *(const f16x8*)(Vbh + (size_t)(kn + vK0 + 1) * HD + vD0);
        }
        // ---- bias loads for THIS chunk (consumed after QK^T) ----
        float4 bb[2][4];
#pragma unroll
        for (int mk = 0; mk < 4; mk++) {
            bb[0][mk] = *(const float4*)(bRow0 + kc + mk * 16);
            bb[1][mk] = *(const float4*)(bRow1 + kc + mk * 16);
        }

        // ---- S^T = K Q^T : st[mk][nq], row=key, col=q ----
        floatx4 st[4][2];
#pragma unroll
        for (int mk = 0; mk < 4; mk++)
#pragma unroll
            for (int nq = 0; nq < 2; nq++)
                st[mk][nq] = (floatx4){0.f, 0.f, 0.f, 0.f};
        __builtin_amdgcn_s_setprio(1);
#pragma unroll
        for (int ks = 0; ks < 2; ks++)
#pragma unroll
            for (int mk = 0; mk < 4; mk++) {
                f16x8 kf = *(const f16x8*)(Ks[buf] + ((ks * 4 + mk) * 64 + lane) * 8);
                st[mk][0] = __builtin_amdgcn_mfma_f32_16x16x32_f16(kf, qf[0][ks], st[mk][0], 0, 0, 0);
                st[mk][1] = __builtin_amdgcn_mfma_f32_16x16x32_f16(kf, qf[1][ks], st[mk][1], 0, 0, 0);
            }
        __builtin_amdgcn_s_setprio(0);

        // ---- softmax per nq: 16 in-lane keys + 4 lanes/q ----
#pragma unroll
        for (int nq = 0; nq < 2; nq++) {
            float rmax = -1e30f;
#pragma unroll
            for (int mk = 0; mk < 4; mk++)
#pragma unroll
                for (int r = 0; r < 4; r++) {
                    float v = st[mk][nq][r] +
                              ((const float*)&bb[nq][mk])[r];
                    st[mk][nq][r] = v;
                    rmax = fmaxf(rmax, v);
                }
            rmax = fmaxf(rmax, __shfl_xor(rmax, 16));
            rmax = fmaxf(rmax, __shfl_xor(rmax, 32));
            float mCur = mRow[nq];
            if (rmax > mCur + 8.f) {             // defer-max (T13)
                const float al = __expf(mCur - rmax);
                lRow[nq] *= al;
#pragma unroll
                for (int m = 0; m < 4; m++)
#pragma unroll
                    for (int i = 0; i < 4; i++) oT[m][nq][i] *= al;
                mCur = rmax;
                mRow[nq] = rmax;
            }
            float rsum = 0.f;
#pragma unroll
            for (int mk = 0; mk < 4; mk++)
#pragma unroll
                for (int r = 0; r < 4; r++) {
                    float e = __expf(st[mk][nq][r] - mCur);   // <= e^8
                    st[mk][nq][r] = e;
                    rsum += e;
                }
            rsum += __shfl_xor(rsum, 16);
            rsum += __shfl_xor(rsum, 32);
            lRow[nq] += rsum;

            // P -> Ps[q][key] (f16x4, verified swizzle)
            const int qv  = nq ? qB : qA;
            const int swp = nq ? swpB : swpA;
            char* pb = psW + (qv << 7) + ((hi4 & 1) << 3);
#pragma unroll
            for (int mk = 0; mk < 4; mk++) {
                const int oct = mk * 2 + (hi4 >> 1);
                f16x4 pc;
#pragma unroll
                for (int r = 0; r < 4; r++) pc[r] = (_Float16)st[mk][nq][r];
                *(f16x4*)(pb + (((oct ^ swp) & 7) << 4)) = pc;
            }
        }

        // ---- O^T += V^T P : oT[m][nq] ----
        __builtin_amdgcn_s_setprio(1);
#pragma unroll
        for (int ks = 0; ks < 2; ks++) {
            f16x8 pa[2];
            pa[0] = *(const f16x8*)(psW + (qA << 7) + ((((ks * 4 + hi4) ^ swpA) & 7) << 4));
            pa[1] = *(const f16x8*)(psW + (qB << 7) + ((((ks * 4 + hi4) ^ swpB) & 7) << 4));
#pragma unroll
            for (int m = 0; m < 4; m++) {
                const int dv = m * 16 + lo16;
                const int swv = (dv & 7) ^ ((dv >> 3) & 7);
                f16x8 vf = *(const f16x8*)((char*)Vt[buf] + (dv << 7)
                                           + ((((ks * 4 + hi4) ^ swv) & 7) << 4));
                oT[m][0] = __builtin_amdgcn_mfma_f32_16x16x32_f16(vf, pa[0], oT[m][0], 0, 0, 0);
                oT[m][1] = __builtin_amdgcn_mfma_f32_16x16x32_f16(vf, pa[1], oT[m][1], 0, 0, 0);
            }
        }
        __builtin_amdgcn_s_setprio(0);
    }

    // ---- epilogue: O^T/l -> fp16 [b,h,s,d]; lane has 4 consecutive d ----
#pragma unroll
    for (int nq = 0; nq < 2; nq++) {
        const float inv = 1.f / lRow[nq];
        const int q = q0 + nq * 16 + lo16;
#pragma unroll
        for (int m = 0; m < 4; m++) {
            f16x4 o4;
#pragma unroll
            for (int i = 0; i < 4; i++) o4[i] = (_Float16)(oT[m][nq][i] * inv);
            *(f16x4*)(attnOut + ((size_t)bh * SL + q) * HD + m * 16 + hi4 * 4) = o4;
        }
    }
}

extern "C" void kernel_launch(void* const* d_in, const int* in_sizes, int n_in,
                              void* d_out, int out_size, void* d_ws, size_t ws_size,
                              hipStream_t stream)
{
    (void)in_sizes; (void)n_in; (void)out_size; (void)ws_size;

    const float* x    = (const float*)d_in[0];
    const float* bias = (const float*)d_in[1];
    const float* Wq   = (const float*)d_in[2];
    const float* Wk   = (const float*)d_in[3];
    const float* Wv   = (const float*)d_in[4];
    const float* Wo   = (const float*)d_in[5];

    const size_t nQKV = (size_t)BS * NH * SL * HD;   // 8388608 elements
    // d_out: Q,K fp16 (2 x 16.78 MB). ws: [V 16.78MB][slotB 16.78MB].
    // slotB = Wh(q,k,v fp16, 6.3MB) during qkv; then attnH (16.78MB) after.
    _Float16* Qh = (_Float16*)d_out;
    _Float16* Kh = Qh + nQKV;
    _Float16* Vh = (_Float16*)d_ws;
    _Float16* slotB = Vh + nQKV;
    _Float16* Wh = slotB;
    _Float16* attnH = slotB;

    // 0) convert Wq/Wk/Wv to fp16
    cvtw_kernel<<<dim3(ED * ED / 1024, 3), 256, 0, stream>>>(Wq, Wk, Wv, Wh);

    // 1) QKV projections: [8192x1024] @ W^T -> fp16 [b,h,s,d]
    dim3 gq(ED / 128, (BS * SL) / 128, 3);
    qkv_kernel<<<gq, 256, 0, stream>>>(x, Wh, Qh, Kh, Vh);

    // 2) MFMA flash attention with rel-pos bias -> fp16 [b,h,s,d] (slotB)
    //    grid (qt, b, h): bias-panel sharers land on the same XCD.
    dim3 ga(SL / 128, BS, NH);
    attn_kernel<<<ga, 256, 0, stream>>>(Qh, Kh, Vh, bias, attnH);

    // 3) output projection (gather A from [b,h,s,d]) -> d_out fp32
    dim3 go(ED / 128, (BS * SL) / 128);
    oproj_kernel<<<go, 256, 0, stream>>>(attnH, Wo, (float*)d_out);
}